// Round 4
// baseline (3263.064 us; speedup 1.0000x reference)
//
#include <hip/hip_runtime.h>

// LSTM_584115552367 — B=65536, T=50, D=17, SLB=30 (runtime).
// Round-4 = round-3 resubmission (round-3 bench died in infra: identical
// "container failed twice" as round-1, and round-2's timing showed 1144 s
// push times; kernel audited clean for OOB/races/barrier-divergence).
//
// Design: 4 threads per batch element (quarter-split over hidden dim) to
// break the grid-capped 1-wave/SIMD occupancy (65536 threads = exactly 1024
// waves). Each quarter computes all 4 gates for its 4-5 of 17 hidden elems;
// h exchanged via double-buffered LDS (stride 17 = conflict-free). Waves are
// quarter-uniform -> weight loads are wave-uniform SGPR-base + imm-offset.
// c-state in registers.

#define Dn 17
#define Tn 50

// g_ws layout (float offsets), all quarter bases 16B-aligned
#define WQ_OFF  0      // [4][34][20] phase-1 weights, j' = gate*5 + ei (padded)
#define CZ_OFF  2720   // [4][17][20] phase-2 folded weights
#define WL_OFF  4080   // [4][17][8]  Wlin quarter (out head), padded 8
#define BS_OFF  4624   // [4][20]     phase-1 bias
#define BC_OFF  4704   // [4][20]     phase-2 folded bias
#define BL_OFF  4784   // [4][8]      b_lin quarter
#define WS_FLOATS 4816

__device__ __align__(16) float g_ws[WS_FLOATS];

__device__ __forceinline__ float sigm_(float v) {
    float e = __expf(-v);
    return __builtin_amdgcn_rcpf(1.0f + e);
}
__device__ __forceinline__ float tanh_(float v) {
    float e = __expf(2.0f * v);
    return 1.0f - 2.0f * __builtin_amdgcn_rcpf(e + 1.0f);
}
__device__ __forceinline__ void fma4(float4& a, float b, const float4 w) {
    a.x = __builtin_fmaf(b, w.x, a.x);
    a.y = __builtin_fmaf(b, w.y, a.y);
    a.z = __builtin_fmaf(b, w.z, a.z);
    a.w = __builtin_fmaf(b, w.w, a.w);
}

__global__ void lstm_setup(const float* __restrict__ W_ih, const float* __restrict__ W_hh,
                           const float* __restrict__ b_ih, const float* __restrict__ b_hh,
                           const float* __restrict__ W_lin, const float* __restrict__ b_lin,
                           const float* __restrict__ m_ih, const float* __restrict__ m_hh)
{
    __shared__ float A[68 * Dn];
    __shared__ float Bm[68 * Dn];
    const int tid = threadIdx.x;
    for (int i = tid; i < 68 * Dn; i += 256) {
        A[i]  = W_ih[i] * m_ih[i];
        Bm[i] = W_hh[i] * m_hh[i];
    }
    __syncthreads();
    // WQ[q][k][j']  (j' = g*5+ei; e = e0(q)+ei; j = g*17+e)
    for (int idx = tid; idx < 4 * 34 * 20; idx += 256) {
        int q = idx / 680, r = idx % 680, k = r / 20, jp = r % 20, g = jp / 5, ei = jp % 5;
        int nE = q ? 4 : 5, e0 = q ? (1 + 4 * q) : 0;
        float v = 0.0f;
        if (ei < nE) {
            int j = g * 17 + e0 + ei;
            v = (k < Dn) ? A[j * Dn + k] : Bm[j * Dn + (k - Dn)];
        }
        g_ws[WQ_OFF + idx] = v;
    }
    // CZ[q][k][j'] = B[j][k] + sum_m A[j][m] * W_lin[m][k]
    for (int idx = tid; idx < 4 * 17 * 20; idx += 256) {
        int q = idx / 340, r = idx % 340, k = r / 20, jp = r % 20, g = jp / 5, ei = jp % 5;
        int nE = q ? 4 : 5, e0 = q ? (1 + 4 * q) : 0;
        float v = 0.0f;
        if (ei < nE) {
            int j = g * 17 + e0 + ei;
            v = Bm[j * Dn + k];
            for (int m = 0; m < Dn; ++m) v = __builtin_fmaf(A[j * Dn + m], W_lin[m * Dn + k], v);
        }
        g_ws[CZ_OFF + idx] = v;
    }
    // WL[q][k][ei] = W_lin[e][k]  (out[e] = sum_k h[k]*W_lin[e][k])
    for (int idx = tid; idx < 4 * 17 * 8; idx += 256) {
        int q = idx / 136, r = idx % 136, k = r / 8, ei = r % 8;
        int nE = q ? 4 : 5, e0 = q ? (1 + 4 * q) : 0;
        g_ws[WL_OFF + idx] = (ei < nE) ? W_lin[(e0 + ei) * Dn + k] : 0.0f;
    }
    // BS / BC
    for (int idx = tid; idx < 4 * 20; idx += 256) {
        int q = idx / 20, jp = idx % 20, g = jp / 5, ei = jp % 5;
        int nE = q ? 4 : 5, e0 = q ? (1 + 4 * q) : 0;
        float vs = 0.0f, vc = 0.0f;
        if (ei < nE) {
            int j = g * 17 + e0 + ei;
            vs = b_ih[j] + b_hh[j];
            vc = vs;
            for (int m = 0; m < Dn; ++m) vc = __builtin_fmaf(A[j * Dn + m], b_lin[m], vc);
        }
        g_ws[BS_OFF + idx] = vs;
        g_ws[BC_OFF + idx] = vc;
    }
    // BL
    for (int idx = tid; idx < 4 * 8; idx += 256) {
        int q = idx / 8, ei = idx % 8;
        int nE = q ? 4 : 5, e0 = q ? (1 + 4 * q) : 0;
        g_ws[BL_OFF + idx] = (ei < nE) ? b_lin[e0 + ei] : 0.0f;
    }
}

__global__ __launch_bounds__(256, 4)
void lstm_main(const float* __restrict__ x,
               const int* __restrict__ slb_p, float* __restrict__ out)
{
    __shared__ float xbuf[2][64 * Dn];   // [parity][b_local*17 + d]
    __shared__ float hbuf[2][64 * Dn];   // [parity][b_local*17 + e]

    const int tid = threadIdx.x;
    const int q   = tid >> 6;            // wave index == quarter role
    const int l   = tid & 63;            // batch element within block
    const int b0  = blockIdx.x * 64;
    const int nE  = q ? 4 : 5;
    const int e0  = q ? (1 + 4 * q) : 0; // e-ranges: [0..4],[5..8],[9..12],[13..16]

    const float4* wq4 = (const float4*)(g_ws + WQ_OFF + q * 680);
    const float4* cz4 = (const float4*)(g_ws + CZ_OFF + q * 340);
    const float4* wl4 = (const float4*)(g_ws + WL_OFF + q * 136);
    const float4* bs4 = (const float4*)(g_ws + BS_OFF + q * 20);
    const float4* bc4 = (const float4*)(g_ws + BC_OFF + q * 20);
    const float4* bl4 = (const float4*)(g_ws + BL_OFF + q * 8);

    // staging map: f = tid + 256*i covers [0, 1088); br = f/17, d = f%17.
    // f == br*17 + d, so LDS write index is just f (xbuf is batch-major).
    int offx[5]; int fi[5]; bool fok[5];
    #pragma unroll
    for (int i = 0; i < 5; ++i) {
        int f  = tid + 256 * i;
        fi[i]  = f;
        fok[i] = (f < 64 * Dn);          // i==4 valid only for wave 0 (uniform)
        int br = f / Dn, d = f - Dn * br;
        offx[i] = ((b0 + br) * Tn) * Dn + d;
    }
    #pragma unroll
    for (int i = 0; i < 5; ++i)
        if (fok[i]) { xbuf[0][fi[i]] = x[offx[i]]; hbuf[0][fi[i]] = 0.0f; }
    __syncthreads();

    const int slb = slb_p[0];
    float c[5];
    #pragma unroll
    for (int e = 0; e < 5; ++e) c[e] = 0.0f;

    int p = 0;

    // ---- phase 1: teacher-forced ----
    for (int t = 0; t < slb; ++t) {
        const bool pre = (t + 1 < slb);
        float gx[5];
        if (pre) {
            #pragma unroll
            for (int i = 0; i < 5; ++i)
                if (fok[i]) gx[i] = x[offx[i] + (t + 1) * Dn];
        }
        const float* xr = &xbuf[p][l * Dn];
        const float* hr = &hbuf[p][l * Dn];
        float4 acc[5];
        #pragma unroll
        for (int j = 0; j < 5; ++j) acc[j] = bs4[j];
        #pragma unroll
        for (int k = 0; k < Dn; ++k) {
            float zk = xr[k];
            #pragma unroll
            for (int j = 0; j < 5; ++j) fma4(acc[j], zk, wq4[k * 5 + j]);
        }
        #pragma unroll
        for (int k = 0; k < Dn; ++k) {
            float zk = hr[k];
            #pragma unroll
            for (int j = 0; j < 5; ++j) fma4(acc[j], zk, wq4[(Dn + k) * 5 + j]);
        }
        const float* af = (const float*)acc;   // [i*5 | f*5 | g*5 | o*5]
        float* hw = &hbuf[p ^ 1][l * Dn + e0];
        #pragma unroll
        for (int ei = 0; ei < 5; ++ei) {
            float cv = __builtin_fmaf(sigm_(af[5 + ei]), c[ei], sigm_(af[ei]) * tanh_(af[10 + ei]));
            c[ei] = cv;
            float hn = sigm_(af[15 + ei]) * tanh_(cv);
            if (ei < nE) hw[ei] = hn;
        }
        if (pre) {
            #pragma unroll
            for (int i = 0; i < 5; ++i)
                if (fok[i]) xbuf[p ^ 1][fi[i]] = gx[i];
        }
        __syncthreads();
        p ^= 1;
    }

    // ---- phase 2: free-running ----
    const int nout = Tn - slb;
    const long obase = (long)(b0 + l) * nout * Dn;
    for (int tp = 0; tp < nout; ++tp) {
        const float* hr = &hbuf[p][l * Dn];
        float4 acc[5];
        #pragma unroll
        for (int j = 0; j < 5; ++j) acc[j] = bc4[j];
        #pragma unroll
        for (int k = 0; k < Dn; ++k) {
            float zk = hr[k];
            #pragma unroll
            for (int j = 0; j < 5; ++j) fma4(acc[j], zk, cz4[k * 5 + j]);
        }
        const float* af = (const float*)acc;
        float* hw = &hbuf[p ^ 1][l * Dn + e0];
        #pragma unroll
        for (int ei = 0; ei < 5; ++ei) {
            float cv = __builtin_fmaf(sigm_(af[5 + ei]), c[ei], sigm_(af[ei]) * tanh_(af[10 + ei]));
            c[ei] = cv;
            float hn = sigm_(af[15 + ei]) * tanh_(cv);
            if (ei < nE) hw[ei] = hn;
        }
        __syncthreads();
        // linear head on the freshly-exchanged full h
        const float* hr2 = &hbuf[p ^ 1][l * Dn];
        float4 o4[2] = { bl4[0], bl4[1] };
        #pragma unroll
        for (int k = 0; k < Dn; ++k) {
            float hk = hr2[k];
            fma4(o4[0], hk, wl4[k * 2 + 0]);
            fma4(o4[1], hk, wl4[k * 2 + 1]);
        }
        const float* of = (const float*)o4;
        float* op = out + obase + (long)tp * Dn + e0;
        #pragma unroll
        for (int ei = 0; ei < 5; ++ei)
            if (ei < nE) op[ei] = of[ei];
        p ^= 1;
    }
}

extern "C" void kernel_launch(void* const* d_in, const int* in_sizes, int n_in,
                              void* d_out, int out_size, void* d_ws, size_t ws_size,
                              hipStream_t stream) {
    (void)in_sizes; (void)n_in; (void)ws_size; (void)out_size; (void)d_ws;
    const float* x     = (const float*)d_in[0];
    const float* W_ih  = (const float*)d_in[1];
    const float* W_hh  = (const float*)d_in[2];
    const float* b_ih  = (const float*)d_in[3];
    const float* b_hh  = (const float*)d_in[4];
    const float* W_lin = (const float*)d_in[5];
    const float* b_lin = (const float*)d_in[6];
    const float* m_ih  = (const float*)d_in[7];
    const float* m_hh  = (const float*)d_in[8];
    const int*   slb   = (const int*)d_in[9];
    float* out = (float*)d_out;

    lstm_setup<<<dim3(1), dim3(256), 0, stream>>>(
        W_ih, W_hh, b_ih, b_hh, W_lin, b_lin, m_ih, m_hh);
    lstm_main<<<dim3(1024), dim3(256), 0, stream>>>(x, slb, out);
}

// Round 5
// 2865.877 us; speedup vs baseline: 1.1386x; 1.1386x over previous
//
#include <hip/hip_runtime.h>

// LSTM_584115552367 — B=65536, T=50, D=17, SLB=30 (runtime).
// Round-5: keep round-4's 4-threads-per-b occupancy win (42.9% occ, 254 µs
// VALU work) but kill the 8.3 GB HBM traffic (45x over round 2) caused by
// 68-B scattered chunk loads/stores at high concurrency. All global access
// is now f-ordered contiguous: x bulk-loaded 4 timesteps at a time (64 b x
// 68 contiguous floats -> 256B/wave-instr), out staged in LDS and bulk-
// stored 4 tps at a time as contiguous 272-B runs per b.

#define Dn 17
#define Tn 50

// g_ws layout (float offsets), all quarter bases 16B-aligned
#define WQ_OFF  0      // [4][34][20] phase-1 weights, j' = gate*5 + ei (padded)
#define CZ_OFF  2720   // [4][17][20] phase-2 folded weights
#define WL_OFF  4080   // [4][17][8]  Wlin quarter (out head), padded 8
#define BS_OFF  4624   // [4][20]     phase-1 bias
#define BC_OFF  4704   // [4][20]     phase-2 folded bias
#define BL_OFF  4784   // [4][8]      b_lin quarter
#define WS_FLOATS 4816

__device__ __align__(16) float g_ws[WS_FLOATS];

__device__ __forceinline__ float sigm_(float v) {
    float e = __expf(-v);
    return __builtin_amdgcn_rcpf(1.0f + e);
}
__device__ __forceinline__ float tanh_(float v) {
    float e = __expf(2.0f * v);
    return 1.0f - 2.0f * __builtin_amdgcn_rcpf(e + 1.0f);
}
__device__ __forceinline__ void fma4(float4& a, float b, const float4 w) {
    a.x = __builtin_fmaf(b, w.x, a.x);
    a.y = __builtin_fmaf(b, w.y, a.y);
    a.z = __builtin_fmaf(b, w.z, a.z);
    a.w = __builtin_fmaf(b, w.w, a.w);
}

__global__ void lstm_setup(const float* __restrict__ W_ih, const float* __restrict__ W_hh,
                           const float* __restrict__ b_ih, const float* __restrict__ b_hh,
                           const float* __restrict__ W_lin, const float* __restrict__ b_lin,
                           const float* __restrict__ m_ih, const float* __restrict__ m_hh)
{
    __shared__ float A[68 * Dn];
    __shared__ float Bm[68 * Dn];
    const int tid = threadIdx.x;
    for (int i = tid; i < 68 * Dn; i += 256) {
        A[i]  = W_ih[i] * m_ih[i];
        Bm[i] = W_hh[i] * m_hh[i];
    }
    __syncthreads();
    // WQ[q][k][j']  (j' = g*5+ei; e = e0(q)+ei; j = g*17+e)
    for (int idx = tid; idx < 4 * 34 * 20; idx += 256) {
        int q = idx / 680, r = idx % 680, k = r / 20, jp = r % 20, g = jp / 5, ei = jp % 5;
        int nE = q ? 4 : 5, e0 = q ? (1 + 4 * q) : 0;
        float v = 0.0f;
        if (ei < nE) {
            int j = g * 17 + e0 + ei;
            v = (k < Dn) ? A[j * Dn + k] : Bm[j * Dn + (k - Dn)];
        }
        g_ws[WQ_OFF + idx] = v;
    }
    // CZ[q][k][j'] = B[j][k] + sum_m A[j][m] * W_lin[m][k]
    for (int idx = tid; idx < 4 * 17 * 20; idx += 256) {
        int q = idx / 340, r = idx % 340, k = r / 20, jp = r % 20, g = jp / 5, ei = jp % 5;
        int nE = q ? 4 : 5, e0 = q ? (1 + 4 * q) : 0;
        float v = 0.0f;
        if (ei < nE) {
            int j = g * 17 + e0 + ei;
            v = Bm[j * Dn + k];
            for (int m = 0; m < Dn; ++m) v = __builtin_fmaf(A[j * Dn + m], W_lin[m * Dn + k], v);
        }
        g_ws[CZ_OFF + idx] = v;
    }
    // WL[q][k][ei] = W_lin[e][k]
    for (int idx = tid; idx < 4 * 17 * 8; idx += 256) {
        int q = idx / 136, r = idx % 136, k = r / 8, ei = r % 8;
        int nE = q ? 4 : 5, e0 = q ? (1 + 4 * q) : 0;
        g_ws[WL_OFF + idx] = (ei < nE) ? W_lin[(e0 + ei) * Dn + k] : 0.0f;
    }
    // BS / BC
    for (int idx = tid; idx < 4 * 20; idx += 256) {
        int q = idx / 20, jp = idx % 20, g = jp / 5, ei = jp % 5;
        int nE = q ? 4 : 5, e0 = q ? (1 + 4 * q) : 0;
        float vs = 0.0f, vc = 0.0f;
        if (ei < nE) {
            int j = g * 17 + e0 + ei;
            vs = b_ih[j] + b_hh[j];
            vc = vs;
            for (int m = 0; m < Dn; ++m) vc = __builtin_fmaf(A[j * Dn + m], b_lin[m], vc);
        }
        g_ws[BS_OFF + idx] = vs;
        g_ws[BC_OFF + idx] = vc;
    }
    // BL
    for (int idx = tid; idx < 4 * 8; idx += 256) {
        int q = idx / 8, ei = idx % 8;
        int nE = q ? 4 : 5, e0 = q ? (1 + 4 * q) : 0;
        g_ws[BL_OFF + idx] = (ei < nE) ? b_lin[e0 + ei] : 0.0f;
    }
}

__global__ __launch_bounds__(256, 4)
void lstm_main(const float* __restrict__ x,
               const int* __restrict__ slb_p, float* __restrict__ out)
{
    __shared__ float sbuf[64 * 69];      // phase1: x 4-step stage; phase2: out 4-step stage
    __shared__ float hbuf[2][64 * Dn];   // double-buffered h exchange

    const int tid = threadIdx.x;
    const int q   = tid >> 6;            // wave index == quarter role
    const int l   = tid & 63;            // batch element within block
    const int b0  = blockIdx.x * 64;
    const int nE  = q ? 4 : 5;
    const int e0  = q ? (1 + 4 * q) : 0; // e-ranges: [0..4],[5..8],[9..12],[13..16]

    const float4* wq4 = (const float4*)(g_ws + WQ_OFF + q * 680);
    const float4* cz4 = (const float4*)(g_ws + CZ_OFF + q * 340);
    const float4* wl4 = (const float4*)(g_ws + WL_OFF + q * 136);
    const float4* bs4 = (const float4*)(g_ws + BS_OFF + q * 20);
    const float4* bc4 = (const float4*)(g_ws + BC_OFF + q * 20);
    const float4* bl4 = (const float4*)(g_ws + BL_OFF + q * 8);

    #pragma unroll
    for (int i = 0; i < 5; ++i) {
        int f = tid + 256 * i;
        if (f < 64 * Dn) hbuf[0][f] = 0.0f;
    }
    __syncthreads();

    const int slb  = slb_p[0];
    const int nout = Tn - slb;

    float c[5];
    #pragma unroll
    for (int e = 0; e < 5; ++e) c[e] = 0.0f;

    int p = 0;

    // ---- phase 1: teacher-forced, 4-step groups ----
    for (int t0 = 0; t0 < slb; t0 += 4) {
        // bulk-load 4 timesteps of x for all 64 b, f-ordered contiguous.
        // 64 b x 68 floats; per b the 68 floats are contiguous in x's row.
        {
            const int base = t0 * Dn;
            #pragma unroll
            for (int i = 0; i < 17; ++i) {
                int f  = tid + 256 * i;          // 0..4351 exact
                int bb = f / 68;                 // compile-time-const divisor
                int rr = f - 68 * bb;
                int ro = base + rr;
                if (ro > Tn * Dn - 1) ro = Tn * Dn - 1;   // row clamp (junk slots never consumed)
                sbuf[bb * 69 + rr] = x[(long)(b0 + bb) * (Tn * Dn) + ro];
            }
        }
        __syncthreads();
        const int gs = (slb - t0 < 4) ? (slb - t0) : 4;
        for (int ts = 0; ts < gs; ++ts) {
            const float* xr = &sbuf[l * 69 + ts * Dn];
            const float* hr = &hbuf[p][l * Dn];
            float4 acc[5];
            #pragma unroll
            for (int j = 0; j < 5; ++j) acc[j] = bs4[j];
            #pragma unroll
            for (int k = 0; k < Dn; ++k) {
                float zk = xr[k];
                #pragma unroll
                for (int j = 0; j < 5; ++j) fma4(acc[j], zk, wq4[k * 5 + j]);
            }
            #pragma unroll
            for (int k = 0; k < Dn; ++k) {
                float zk = hr[k];
                #pragma unroll
                for (int j = 0; j < 5; ++j) fma4(acc[j], zk, wq4[(Dn + k) * 5 + j]);
            }
            const float* af = (const float*)acc;   // [i*5 | f*5 | g*5 | o*5]
            float* hw = &hbuf[p ^ 1][l * Dn + e0];
            #pragma unroll
            for (int ei = 0; ei < 5; ++ei) {
                float cv = __builtin_fmaf(sigm_(af[5 + ei]), c[ei], sigm_(af[ei]) * tanh_(af[10 + ei]));
                c[ei] = cv;
                float hn = sigm_(af[15 + ei]) * tanh_(cv);
                if (ei < nE) hw[ei] = hn;
            }
            __syncthreads();
            p ^= 1;
        }
    }

    // ---- phase 2: free-running, 4-step groups with staged coalesced output ----
    for (int tp0 = 0; tp0 < nout; tp0 += 4) {
        const int gs = (nout - tp0 < 4) ? (nout - tp0) : 4;
        for (int ts = 0; ts < gs; ++ts) {
            const float* hr = &hbuf[p][l * Dn];
            float4 acc[5];
            #pragma unroll
            for (int j = 0; j < 5; ++j) acc[j] = bc4[j];
            #pragma unroll
            for (int k = 0; k < Dn; ++k) {
                float zk = hr[k];
                #pragma unroll
                for (int j = 0; j < 5; ++j) fma4(acc[j], zk, cz4[k * 5 + j]);
            }
            const float* af = (const float*)acc;
            float* hw = &hbuf[p ^ 1][l * Dn + e0];
            #pragma unroll
            for (int ei = 0; ei < 5; ++ei) {
                float cv = __builtin_fmaf(sigm_(af[5 + ei]), c[ei], sigm_(af[ei]) * tanh_(af[10 + ei]));
                c[ei] = cv;
                float hn = sigm_(af[15 + ei]) * tanh_(cv);
                if (ei < nE) hw[ei] = hn;
            }
            __syncthreads();
            // head on the freshly-exchanged full h; stash result slice in LDS
            const float* hr2 = &hbuf[p ^ 1][l * Dn];
            float4 o4[2] = { bl4[0], bl4[1] };
            #pragma unroll
            for (int k = 0; k < Dn; ++k) {
                float hk = hr2[k];
                fma4(o4[0], hk, wl4[k * 2 + 0]);
                fma4(o4[1], hk, wl4[k * 2 + 1]);
            }
            const float* of = (const float*)o4;
            float* ow = &sbuf[l * 69 + ts * Dn + e0];
            #pragma unroll
            for (int ei = 0; ei < 5; ++ei)
                if (ei < nE) ow[ei] = of[ei];
            p ^= 1;
        }
        __syncthreads();   // sbuf tile complete across all waves
        // bulk store: per b, gs*17 contiguous floats of the out row
        if (gs == 4) {
            #pragma unroll
            for (int i = 0; i < 17; ++i) {
                int f  = tid + 256 * i;          // 0..4351 exact
                int bb = f / 68;
                int rr = f - 68 * bb;
                out[(long)(b0 + bb) * (nout * Dn) + tp0 * Dn + rr] = sbuf[bb * 69 + rr];
            }
        } else {
            const int cnt = gs * Dn;
            for (int f = tid; f < 64 * cnt; f += 256) {
                int bb = f / cnt;
                int rr = f - cnt * bb;
                out[(long)(b0 + bb) * (nout * Dn) + tp0 * Dn + rr] = sbuf[bb * 69 + rr];
            }
        }
        // next group's sbuf writes occur after its step-0 barrier -> no extra barrier
    }
}

extern "C" void kernel_launch(void* const* d_in, const int* in_sizes, int n_in,
                              void* d_out, int out_size, void* d_ws, size_t ws_size,
                              hipStream_t stream) {
    (void)in_sizes; (void)n_in; (void)ws_size; (void)out_size; (void)d_ws;
    const float* x     = (const float*)d_in[0];
    const float* W_ih  = (const float*)d_in[1];
    const float* W_hh  = (const float*)d_in[2];
    const float* b_ih  = (const float*)d_in[3];
    const float* b_hh  = (const float*)d_in[4];
    const float* W_lin = (const float*)d_in[5];
    const float* b_lin = (const float*)d_in[6];
    const float* m_ih  = (const float*)d_in[7];
    const float* m_hh  = (const float*)d_in[8];
    const int*   slb   = (const int*)d_in[9];
    float* out = (float*)d_out;

    lstm_setup<<<dim3(1), dim3(256), 0, stream>>>(
        W_ih, W_hh, b_ih, b_hh, W_lin, b_lin, m_ih, m_hh);
    lstm_main<<<dim3(1024), dim3(256), 0, stream>>>(x, slb, out);
}

// Round 6
// 1626.113 us; speedup vs baseline: 2.0067x; 1.7624x over previous
//
#include <hip/hip_runtime.h>

// LSTM_584115552367 — B=65536, T=50, D=17, SLB=30 (runtime).
// Round-6 = round-5 minus the scratch spill. Rounds 4/5 read acc/o4 through
// `(const float*)acc` casts -> SROA defeated -> acc spilled to scratch ->
// ~6 GB phantom WRITE + ~2 GB phantom FETCH (scratch thrashes 4MB/XCD L2),
// VGPR 120->64. Fix: vector-component extraction with compile-time indices
// (round-2-proven). Everything else identical to round 5.

#define Dn 17
#define Tn 50

// g_ws layout (float offsets), all quarter bases 16B-aligned
#define WQ_OFF  0      // [4][34][20] phase-1 weights, j' = gate*5 + ei (padded)
#define CZ_OFF  2720   // [4][17][20] phase-2 folded weights
#define WL_OFF  4080   // [4][17][8]  Wlin quarter (out head), padded 8
#define BS_OFF  4624   // [4][20]     phase-1 bias
#define BC_OFF  4704   // [4][20]     phase-2 folded bias
#define BL_OFF  4784   // [4][8]      b_lin quarter
#define WS_FLOATS 4816

__device__ __align__(16) float g_ws[WS_FLOATS];

__device__ __forceinline__ float sigm_(float v) {
    float e = __expf(-v);
    return __builtin_amdgcn_rcpf(1.0f + e);
}
__device__ __forceinline__ float tanh_(float v) {
    float e = __expf(2.0f * v);
    return 1.0f - 2.0f * __builtin_amdgcn_rcpf(e + 1.0f);
}
__device__ __forceinline__ float getc(const float4 v, int c) {
    return c == 0 ? v.x : c == 1 ? v.y : c == 2 ? v.z : v.w;
}
__device__ __forceinline__ void fma4(float4& a, float b, const float4 w) {
    a.x = __builtin_fmaf(b, w.x, a.x);
    a.y = __builtin_fmaf(b, w.y, a.y);
    a.z = __builtin_fmaf(b, w.z, a.z);
    a.w = __builtin_fmaf(b, w.w, a.w);
}

__global__ void lstm_setup(const float* __restrict__ W_ih, const float* __restrict__ W_hh,
                           const float* __restrict__ b_ih, const float* __restrict__ b_hh,
                           const float* __restrict__ W_lin, const float* __restrict__ b_lin,
                           const float* __restrict__ m_ih, const float* __restrict__ m_hh)
{
    __shared__ float A[68 * Dn];
    __shared__ float Bm[68 * Dn];
    const int tid = threadIdx.x;
    for (int i = tid; i < 68 * Dn; i += 256) {
        A[i]  = W_ih[i] * m_ih[i];
        Bm[i] = W_hh[i] * m_hh[i];
    }
    __syncthreads();
    // WQ[q][k][j']  (j' = g*5+ei; e = e0(q)+ei; j = g*17+e)
    for (int idx = tid; idx < 4 * 34 * 20; idx += 256) {
        int q = idx / 680, r = idx % 680, k = r / 20, jp = r % 20, g = jp / 5, ei = jp % 5;
        int nE = q ? 4 : 5, e0 = q ? (1 + 4 * q) : 0;
        float v = 0.0f;
        if (ei < nE) {
            int j = g * 17 + e0 + ei;
            v = (k < Dn) ? A[j * Dn + k] : Bm[j * Dn + (k - Dn)];
        }
        g_ws[WQ_OFF + idx] = v;
    }
    // CZ[q][k][j'] = B[j][k] + sum_m A[j][m] * W_lin[m][k]
    for (int idx = tid; idx < 4 * 17 * 20; idx += 256) {
        int q = idx / 340, r = idx % 340, k = r / 20, jp = r % 20, g = jp / 5, ei = jp % 5;
        int nE = q ? 4 : 5, e0 = q ? (1 + 4 * q) : 0;
        float v = 0.0f;
        if (ei < nE) {
            int j = g * 17 + e0 + ei;
            v = Bm[j * Dn + k];
            for (int m = 0; m < Dn; ++m) v = __builtin_fmaf(A[j * Dn + m], W_lin[m * Dn + k], v);
        }
        g_ws[CZ_OFF + idx] = v;
    }
    // WL[q][k][ei] = W_lin[e][k]
    for (int idx = tid; idx < 4 * 17 * 8; idx += 256) {
        int q = idx / 136, r = idx % 136, k = r / 8, ei = r % 8;
        int nE = q ? 4 : 5, e0 = q ? (1 + 4 * q) : 0;
        g_ws[WL_OFF + idx] = (ei < nE) ? W_lin[(e0 + ei) * Dn + k] : 0.0f;
    }
    // BS / BC
    for (int idx = tid; idx < 4 * 20; idx += 256) {
        int q = idx / 20, jp = idx % 20, g = jp / 5, ei = jp % 5;
        int nE = q ? 4 : 5, e0 = q ? (1 + 4 * q) : 0;
        float vs = 0.0f, vc = 0.0f;
        if (ei < nE) {
            int j = g * 17 + e0 + ei;
            vs = b_ih[j] + b_hh[j];
            vc = vs;
            for (int m = 0; m < Dn; ++m) vc = __builtin_fmaf(A[j * Dn + m], b_lin[m], vc);
        }
        g_ws[BS_OFF + idx] = vs;
        g_ws[BC_OFF + idx] = vc;
    }
    // BL
    for (int idx = tid; idx < 4 * 8; idx += 256) {
        int q = idx / 8, ei = idx % 8;
        int nE = q ? 4 : 5, e0 = q ? (1 + 4 * q) : 0;
        g_ws[BL_OFF + idx] = (ei < nE) ? b_lin[e0 + ei] : 0.0f;
    }
}

__global__ __launch_bounds__(256, 4)
void lstm_main(const float* __restrict__ x,
               const int* __restrict__ slb_p, float* __restrict__ out)
{
    __shared__ float sbuf[64 * 69];      // phase1: x 4-step stage; phase2: out 4-step stage
    __shared__ float hbuf[2][64 * Dn];   // double-buffered h exchange

    const int tid = threadIdx.x;
    const int q   = tid >> 6;            // wave index == quarter role
    const int l   = tid & 63;            // batch element within block
    const int b0  = blockIdx.x * 64;
    const int nE  = q ? 4 : 5;
    const int e0  = q ? (1 + 4 * q) : 0; // e-ranges: [0..4],[5..8],[9..12],[13..16]

    const float4* wq4 = (const float4*)(g_ws + WQ_OFF + q * 680);
    const float4* cz4 = (const float4*)(g_ws + CZ_OFF + q * 340);
    const float4* wl4 = (const float4*)(g_ws + WL_OFF + q * 136);
    const float4* bs4 = (const float4*)(g_ws + BS_OFF + q * 20);
    const float4* bc4 = (const float4*)(g_ws + BC_OFF + q * 20);
    const float4* bl4 = (const float4*)(g_ws + BL_OFF + q * 8);

    #pragma unroll
    for (int i = 0; i < 5; ++i) {
        int f = tid + 256 * i;
        if (f < 64 * Dn) hbuf[0][f] = 0.0f;
    }
    __syncthreads();

    const int slb  = slb_p[0];
    const int nout = Tn - slb;

    float c[5];
    #pragma unroll
    for (int e = 0; e < 5; ++e) c[e] = 0.0f;

    int p = 0;

    // ---- phase 1: teacher-forced, 4-step groups ----
    for (int t0 = 0; t0 < slb; t0 += 4) {
        // bulk-load 4 timesteps of x for all 64 b, f-ordered contiguous
        {
            const int base = t0 * Dn;
            #pragma unroll
            for (int i = 0; i < 17; ++i) {
                int f  = tid + 256 * i;          // 0..4351 exact
                int bb = f / 68;
                int rr = f - 68 * bb;
                int ro = base + rr;
                if (ro > Tn * Dn - 1) ro = Tn * Dn - 1;   // row clamp (junk never consumed)
                sbuf[bb * 69 + rr] = x[(long)(b0 + bb) * (Tn * Dn) + ro];
            }
        }
        __syncthreads();
        const int gs = (slb - t0 < 4) ? (slb - t0) : 4;
        for (int ts = 0; ts < gs; ++ts) {
            const float* xr = &sbuf[l * 69 + ts * Dn];
            const float* hr = &hbuf[p][l * Dn];
            float4 acc[5];
            #pragma unroll
            for (int j = 0; j < 5; ++j) acc[j] = bs4[j];
            #pragma unroll
            for (int k = 0; k < Dn; ++k) {
                float zk = xr[k];
                #pragma unroll
                for (int j = 0; j < 5; ++j) fma4(acc[j], zk, wq4[k * 5 + j]);
            }
            #pragma unroll
            for (int k = 0; k < Dn; ++k) {
                float zk = hr[k];
                #pragma unroll
                for (int j = 0; j < 5; ++j) fma4(acc[j], zk, wq4[(Dn + k) * 5 + j]);
            }
            float* hw = &hbuf[p ^ 1][l * Dn + e0];
            #pragma unroll
            for (int ei = 0; ei < 5; ++ei) {   // j' = gate*5+ei; all indices fold to consts
                float gi = getc(acc[(0 + ei) >> 2], (0 + ei) & 3);
                float gf = getc(acc[(5 + ei) >> 2], (5 + ei) & 3);
                float gg = getc(acc[(10 + ei) >> 2], (10 + ei) & 3);
                float go = getc(acc[(15 + ei) >> 2], (15 + ei) & 3);
                float cv = __builtin_fmaf(sigm_(gf), c[ei], sigm_(gi) * tanh_(gg));
                c[ei] = cv;
                float hn = sigm_(go) * tanh_(cv);
                if (ei < nE) hw[ei] = hn;
            }
            __syncthreads();
            p ^= 1;
        }
    }

    // ---- phase 2: free-running, 4-step groups with staged coalesced output ----
    for (int tp0 = 0; tp0 < nout; tp0 += 4) {
        const int gs = (nout - tp0 < 4) ? (nout - tp0) : 4;
        for (int ts = 0; ts < gs; ++ts) {
            const float* hr = &hbuf[p][l * Dn];
            float4 acc[5];
            #pragma unroll
            for (int j = 0; j < 5; ++j) acc[j] = bc4[j];
            #pragma unroll
            for (int k = 0; k < Dn; ++k) {
                float zk = hr[k];
                #pragma unroll
                for (int j = 0; j < 5; ++j) fma4(acc[j], zk, cz4[k * 5 + j]);
            }
            float* hw = &hbuf[p ^ 1][l * Dn + e0];
            #pragma unroll
            for (int ei = 0; ei < 5; ++ei) {
                float gi = getc(acc[(0 + ei) >> 2], (0 + ei) & 3);
                float gf = getc(acc[(5 + ei) >> 2], (5 + ei) & 3);
                float gg = getc(acc[(10 + ei) >> 2], (10 + ei) & 3);
                float go = getc(acc[(15 + ei) >> 2], (15 + ei) & 3);
                float cv = __builtin_fmaf(sigm_(gf), c[ei], sigm_(gi) * tanh_(gg));
                c[ei] = cv;
                float hn = sigm_(go) * tanh_(cv);
                if (ei < nE) hw[ei] = hn;
            }
            __syncthreads();
            // head on the freshly-exchanged full h; stash result slice in LDS
            const float* hr2 = &hbuf[p ^ 1][l * Dn];
            float4 o4[2] = { bl4[0], bl4[1] };
            #pragma unroll
            for (int k = 0; k < Dn; ++k) {
                float hk = hr2[k];
                fma4(o4[0], hk, wl4[k * 2 + 0]);
                fma4(o4[1], hk, wl4[k * 2 + 1]);
            }
            float* ow = &sbuf[l * 69 + ts * Dn + e0];
            #pragma unroll
            for (int ei = 0; ei < 5; ++ei)
                if (ei < nE) ow[ei] = getc(o4[ei >> 2], ei & 3);
            p ^= 1;
        }
        __syncthreads();   // sbuf tile complete across all waves
        // bulk store: per b, gs*17 contiguous floats of the out row
        if (gs == 4) {
            #pragma unroll
            for (int i = 0; i < 17; ++i) {
                int f  = tid + 256 * i;          // 0..4351 exact
                int bb = f / 68;
                int rr = f - 68 * bb;
                out[(long)(b0 + bb) * (nout * Dn) + tp0 * Dn + rr] = sbuf[bb * 69 + rr];
            }
        } else {
            const int cnt = gs * Dn;
            for (int f = tid; f < 64 * cnt; f += 256) {
                int bb = f / cnt;
                int rr = f - cnt * bb;
                out[(long)(b0 + bb) * (nout * Dn) + tp0 * Dn + rr] = sbuf[bb * 69 + rr];
            }
        }
        // next group's sbuf writes occur after its step-0 barrier -> no extra barrier
    }
}

extern "C" void kernel_launch(void* const* d_in, const int* in_sizes, int n_in,
                              void* d_out, int out_size, void* d_ws, size_t ws_size,
                              hipStream_t stream) {
    (void)in_sizes; (void)n_in; (void)ws_size; (void)out_size; (void)d_ws;
    const float* x     = (const float*)d_in[0];
    const float* W_ih  = (const float*)d_in[1];
    const float* W_hh  = (const float*)d_in[2];
    const float* b_ih  = (const float*)d_in[3];
    const float* b_hh  = (const float*)d_in[4];
    const float* W_lin = (const float*)d_in[5];
    const float* b_lin = (const float*)d_in[6];
    const float* m_ih  = (const float*)d_in[7];
    const float* m_hh  = (const float*)d_in[8];
    const int*   slb   = (const int*)d_in[9];
    float* out = (float*)d_out;

    lstm_setup<<<dim3(1), dim3(256), 0, stream>>>(
        W_ih, W_hh, b_ih, b_hh, W_lin, b_lin, m_ih, m_hh);
    lstm_main<<<dim3(1024), dim3(256), 0, stream>>>(x, slb, out);
}

// Round 7
// 1190.975 us; speedup vs baseline: 2.7398x; 1.3654x over previous
//
#include <hip/hip_runtime.h>

// LSTM_584115552367 — B=65536, T=50, D=17, SLB=30 (runtime).
// Round-7: weights move to LDS (broadcast ds_read_b128, conflict-free,
// ZERO global weight traffic) while keeping the 4-thread/b split
// (16 waves/CU), register h/c, and bulk-coalesced x/out staging.
// Rationale: every 4-blocks/CU global-weight variant (r4/5/6) showed
// GB-scale phantom HBM traffic (2.4 GB WRITE vs 89 MB output) that fully
// explains dur; LDS-weight variants never did. FMA core is ~255 µs
// (VALUBusy x dur, stable across rounds) — this removes everything else.
// LDS = 19.3K weights + 9.0K sbuf (2-step x/out groups) + 8.7K hbuf
// = 36.9 KB -> all 4 blocks/CU resident.

#define Dn 17
#define Tn 50

// g_ws layout (float offsets), all quarter bases 16B-aligned
#define WQ_OFF  0      // [4][34][20] phase-1 weights, j' = gate*5 + ei (padded)
#define CZ_OFF  2720   // [4][17][20] phase-2 folded weights
#define WL_OFF  4080   // [4][17][8]  Wlin quarter (out head), padded 8
#define BS_OFF  4624   // [4][20]     phase-1 bias
#define BC_OFF  4704   // [4][20]     phase-2 folded bias
#define BL_OFF  4784   // [4][8]      b_lin quarter
#define WS_FLOATS 4816

#define SROW 35        // sbuf row stride (2 steps x 17 = 34, +1 odd pad)

__device__ __align__(16) float g_ws[WS_FLOATS];

__device__ __forceinline__ float sigm_(float v) {
    float e = __expf(-v);
    return __builtin_amdgcn_rcpf(1.0f + e);
}
__device__ __forceinline__ float tanh_(float v) {
    float e = __expf(2.0f * v);
    return 1.0f - 2.0f * __builtin_amdgcn_rcpf(e + 1.0f);
}
__device__ __forceinline__ float getc(const float4 v, int c) {
    return c == 0 ? v.x : c == 1 ? v.y : c == 2 ? v.z : v.w;
}
__device__ __forceinline__ void fma4(float4& a, float b, const float4 w) {
    a.x = __builtin_fmaf(b, w.x, a.x);
    a.y = __builtin_fmaf(b, w.y, a.y);
    a.z = __builtin_fmaf(b, w.z, a.z);
    a.w = __builtin_fmaf(b, w.w, a.w);
}

__global__ void lstm_setup(const float* __restrict__ W_ih, const float* __restrict__ W_hh,
                           const float* __restrict__ b_ih, const float* __restrict__ b_hh,
                           const float* __restrict__ W_lin, const float* __restrict__ b_lin,
                           const float* __restrict__ m_ih, const float* __restrict__ m_hh)
{
    __shared__ float A[68 * Dn];
    __shared__ float Bm[68 * Dn];
    const int tid = threadIdx.x;
    for (int i = tid; i < 68 * Dn; i += 256) {
        A[i]  = W_ih[i] * m_ih[i];
        Bm[i] = W_hh[i] * m_hh[i];
    }
    __syncthreads();
    // WQ[q][k][j']  (j' = g*5+ei; e = e0(q)+ei; j = g*17+e)
    for (int idx = tid; idx < 4 * 34 * 20; idx += 256) {
        int q = idx / 680, r = idx % 680, k = r / 20, jp = r % 20, g = jp / 5, ei = jp % 5;
        int nE = q ? 4 : 5, e0 = q ? (1 + 4 * q) : 0;
        float v = 0.0f;
        if (ei < nE) {
            int j = g * 17 + e0 + ei;
            v = (k < Dn) ? A[j * Dn + k] : Bm[j * Dn + (k - Dn)];
        }
        g_ws[WQ_OFF + idx] = v;
    }
    // CZ[q][k][j'] = B[j][k] + sum_m A[j][m] * W_lin[m][k]
    for (int idx = tid; idx < 4 * 17 * 20; idx += 256) {
        int q = idx / 340, r = idx % 340, k = r / 20, jp = r % 20, g = jp / 5, ei = jp % 5;
        int nE = q ? 4 : 5, e0 = q ? (1 + 4 * q) : 0;
        float v = 0.0f;
        if (ei < nE) {
            int j = g * 17 + e0 + ei;
            v = Bm[j * Dn + k];
            for (int m = 0; m < Dn; ++m) v = __builtin_fmaf(A[j * Dn + m], W_lin[m * Dn + k], v);
        }
        g_ws[CZ_OFF + idx] = v;
    }
    // WL[q][k][ei] = W_lin[e][k]
    for (int idx = tid; idx < 4 * 17 * 8; idx += 256) {
        int q = idx / 136, r = idx % 136, k = r / 8, ei = r % 8;
        int nE = q ? 4 : 5, e0 = q ? (1 + 4 * q) : 0;
        g_ws[WL_OFF + idx] = (ei < nE) ? W_lin[(e0 + ei) * Dn + k] : 0.0f;
    }
    // BS / BC
    for (int idx = tid; idx < 4 * 20; idx += 256) {
        int q = idx / 20, jp = idx % 20, g = jp / 5, ei = jp % 5;
        int nE = q ? 4 : 5, e0 = q ? (1 + 4 * q) : 0;
        float vs = 0.0f, vc = 0.0f;
        if (ei < nE) {
            int j = g * 17 + e0 + ei;
            vs = b_ih[j] + b_hh[j];
            vc = vs;
            for (int m = 0; m < Dn; ++m) vc = __builtin_fmaf(A[j * Dn + m], b_lin[m], vc);
        }
        g_ws[BS_OFF + idx] = vs;
        g_ws[BC_OFF + idx] = vc;
    }
    // BL
    for (int idx = tid; idx < 4 * 8; idx += 256) {
        int q = idx / 8, ei = idx % 8;
        int nE = q ? 4 : 5, e0 = q ? (1 + 4 * q) : 0;
        g_ws[BL_OFF + idx] = (ei < nE) ? b_lin[e0 + ei] : 0.0f;
    }
}

__global__ __launch_bounds__(256, 4)
void lstm_main(const float* __restrict__ x,
               const int* __restrict__ slb_p, float* __restrict__ out)
{
    __shared__ __align__(16) float sW[WS_FLOATS];   // all prepared weights (19.3 KB)
    __shared__ float sbuf[64 * SROW];               // x / out staging, 2-step groups
    __shared__ float hbuf[2][64 * Dn];              // double-buffered h exchange

    const int tid = threadIdx.x;
    const int q   = tid >> 6;            // wave index == quarter role
    const int l   = tid & 63;            // batch element within block
    const int b0  = blockIdx.x * 64;
    const int nE  = q ? 4 : 5;
    const int e0  = q ? (1 + 4 * q) : 0; // e-ranges: [0..4],[5..8],[9..12],[13..16]

    // stage all weights into LDS once (coalesced, 19 iters)
    for (int i = tid; i < WS_FLOATS; i += 256) sW[i] = g_ws[i];

    const float4* wq4 = (const float4*)(sW + WQ_OFF + q * 680);
    const float4* cz4 = (const float4*)(sW + CZ_OFF + q * 340);
    const float4* wl4 = (const float4*)(sW + WL_OFF + q * 136);
    const float4* bs4 = (const float4*)(sW + BS_OFF + q * 20);
    const float4* bc4 = (const float4*)(sW + BC_OFF + q * 20);
    const float4* bl4 = (const float4*)(sW + BL_OFF + q * 8);

    #pragma unroll
    for (int i = 0; i < 5; ++i) {
        int f = tid + 256 * i;
        if (f < 64 * Dn) hbuf[0][f] = 0.0f;
    }
    __syncthreads();

    const int slb  = slb_p[0];
    const int nout = Tn - slb;

    float c[5];
    #pragma unroll
    for (int e = 0; e < 5; ++e) c[e] = 0.0f;

    int p = 0;

    // ---- phase 1: teacher-forced, 2-step groups ----
    for (int t0 = 0; t0 < slb; t0 += 2) {
        // bulk-load 2 timesteps of x for all 64 b, f-ordered contiguous.
        {
            const int base = t0 * Dn;
            #pragma unroll
            for (int i = 0; i < 9; ++i) {
                int f = tid + 256 * i;
                if (f < 64 * 34) {
                    int bb = f / 34;
                    int rr = f - 34 * bb;
                    // ro = t0*17 + rr <= (slb-1)*17 + 33 <= 849 always in-row
                    sbuf[bb * SROW + rr] = x[(long)(b0 + bb) * (Tn * Dn) + base + rr];
                }
            }
        }
        __syncthreads();
        const int gs = (slb - t0 < 2) ? (slb - t0) : 2;
        for (int ts = 0; ts < gs; ++ts) {
            const float* xr = &sbuf[l * SROW + ts * Dn];
            const float* hr = &hbuf[p][l * Dn];
            float4 acc[5];
            #pragma unroll
            for (int j = 0; j < 5; ++j) acc[j] = bs4[j];
            #pragma unroll
            for (int k = 0; k < Dn; ++k) {
                float zk = xr[k];
                const float4* w4 = wq4 + k * 5;
                #pragma unroll
                for (int j = 0; j < 5; ++j) fma4(acc[j], zk, w4[j]);
            }
            #pragma unroll
            for (int k = 0; k < Dn; ++k) {
                float zk = hr[k];
                const float4* w4 = wq4 + (Dn + k) * 5;
                #pragma unroll
                for (int j = 0; j < 5; ++j) fma4(acc[j], zk, w4[j]);
            }
            float* hw = &hbuf[p ^ 1][l * Dn + e0];
            #pragma unroll
            for (int ei = 0; ei < 5; ++ei) {   // j' = gate*5+ei; indices fold to consts
                float gi = getc(acc[(0 + ei) >> 2], (0 + ei) & 3);
                float gf = getc(acc[(5 + ei) >> 2], (5 + ei) & 3);
                float gg = getc(acc[(10 + ei) >> 2], (10 + ei) & 3);
                float go = getc(acc[(15 + ei) >> 2], (15 + ei) & 3);
                float cv = __builtin_fmaf(sigm_(gf), c[ei], sigm_(gi) * tanh_(gg));
                c[ei] = cv;
                float hn = sigm_(go) * tanh_(cv);
                if (ei < nE) hw[ei] = hn;
            }
            __syncthreads();
            p ^= 1;
        }
    }

    // ---- phase 2: free-running, 2-step groups with staged coalesced output ----
    for (int tp0 = 0; tp0 < nout; tp0 += 2) {
        const int gs = (nout - tp0 < 2) ? (nout - tp0) : 2;
        for (int ts = 0; ts < gs; ++ts) {
            const float* hr = &hbuf[p][l * Dn];
            float4 acc[5];
            #pragma unroll
            for (int j = 0; j < 5; ++j) acc[j] = bc4[j];
            #pragma unroll
            for (int k = 0; k < Dn; ++k) {
                float zk = hr[k];
                const float4* w4 = cz4 + k * 5;
                #pragma unroll
                for (int j = 0; j < 5; ++j) fma4(acc[j], zk, w4[j]);
            }
            float* hw = &hbuf[p ^ 1][l * Dn + e0];
            #pragma unroll
            for (int ei = 0; ei < 5; ++ei) {
                float gi = getc(acc[(0 + ei) >> 2], (0 + ei) & 3);
                float gf = getc(acc[(5 + ei) >> 2], (5 + ei) & 3);
                float gg = getc(acc[(10 + ei) >> 2], (10 + ei) & 3);
                float go = getc(acc[(15 + ei) >> 2], (15 + ei) & 3);
                float cv = __builtin_fmaf(sigm_(gf), c[ei], sigm_(gi) * tanh_(gg));
                c[ei] = cv;
                float hn = sigm_(go) * tanh_(cv);
                if (ei < nE) hw[ei] = hn;
            }
            __syncthreads();
            // head on the freshly-exchanged full h; stash slice into sbuf
            const float* hr2 = &hbuf[p ^ 1][l * Dn];
            float4 o4[2] = { bl4[0], bl4[1] };
            #pragma unroll
            for (int k = 0; k < Dn; ++k) {
                float hk = hr2[k];
                fma4(o4[0], hk, wl4[k * 2 + 0]);
                fma4(o4[1], hk, wl4[k * 2 + 1]);
            }
            float* ow = &sbuf[l * SROW + ts * Dn + e0];
            #pragma unroll
            for (int ei = 0; ei < 5; ++ei)
                if (ei < nE) ow[ei] = getc(o4[ei >> 2], ei & 3);
            p ^= 1;
        }
        __syncthreads();   // sbuf tile complete across all waves
        // bulk store: per b, gs*17 contiguous floats of the out row
        if (gs == 2) {
            #pragma unroll
            for (int i = 0; i < 9; ++i) {
                int f = tid + 256 * i;
                if (f < 64 * 34) {
                    int bb = f / 34;
                    int rr = f - 34 * bb;
                    out[(long)(b0 + bb) * (nout * Dn) + tp0 * Dn + rr] = sbuf[bb * SROW + rr];
                }
            }
        } else {
            for (int f = tid; f < 64 * Dn; f += 256) {
                int bb = f / Dn;
                int rr = f - Dn * bb;
                out[(long)(b0 + bb) * (nout * Dn) + tp0 * Dn + rr] = sbuf[bb * SROW + rr];
            }
        }
        // next group's sbuf writes occur after its own compute barrier, and
        // this group's sbuf reads complete before each wave reaches it -> safe
    }
}

extern "C" void kernel_launch(void* const* d_in, const int* in_sizes, int n_in,
                              void* d_out, int out_size, void* d_ws, size_t ws_size,
                              hipStream_t stream) {
    (void)in_sizes; (void)n_in; (void)ws_size; (void)out_size; (void)d_ws;
    const float* x     = (const float*)d_in[0];
    const float* W_ih  = (const float*)d_in[1];
    const float* W_hh  = (const float*)d_in[2];
    const float* b_ih  = (const float*)d_in[3];
    const float* b_hh  = (const float*)d_in[4];
    const float* W_lin = (const float*)d_in[5];
    const float* b_lin = (const float*)d_in[6];
    const float* m_ih  = (const float*)d_in[7];
    const float* m_hh  = (const float*)d_in[8];
    const int*   slb   = (const int*)d_in[9];
    float* out = (float*)d_out;

    lstm_setup<<<dim3(1), dim3(256), 0, stream>>>(
        W_ih, W_hh, b_ih, b_hh, W_lin, b_lin, m_ih, m_hh);
    lstm_main<<<dim3(1024), dim3(256), 0, stream>>>(x, slb, out);
}